// Round 1
// baseline (344.786 us; speedup 1.0000x reference)
//
#include <hip/hip_runtime.h>
#include <math.h>

#define BB 4
#define LL 2048
#define TCH 32          // scan chunk length
#define NCH (LL/TCH)    // 64 chunks per sequence

__device__ __forceinline__ float sigmoidf_(float x){ return 1.0f/(1.0f+__expf(-x)); }

// ---------------- K0: rmsnorm (shared rstd, norm weights folded into W) ---------
__global__ void k_rmsnorm(const float* __restrict__ x, float* __restrict__ xhat){
  int p = blockIdx.x;           // 0..B*L-1
  int t = threadIdx.x;          // 0..63 (one wave)
  float v = x[p*64 + t];
  float s = v*v;
  for (int m=32; m>0; m>>=1) s += __shfl_xor(s, m, 64);
  float rstd = rsqrtf(s*(1.0f/64.0f) + 1e-5f);
  xhat[p*64+t] = v*rstd;
}

// ---------------- K0b: fold norm weights into in_proj weights -------------------
__global__ void k_fold(const float* __restrict__ wf, const float* __restrict__ nwf,
                       const float* __restrict__ wb, const float* __restrict__ nwb,
                       float* __restrict__ Wn){
  int i = blockIdx.x*256 + threadIdx.x;   // 0..65535 = 2*512*64
  int dm = i & 63;
  int e  = (i>>6) & 511;
  int dir = i>>15;
  const float* w  = dir ? wb  : wf;
  const float* nw = dir ? nwb : nwf;
  Wn[i] = w[e*64+dm]*nw[dm];
}

// ---------------- K1: in_proj GEMM (8192x64 @ 64x1024), SiLU fused on z half ----
__global__ __launch_bounds__(256) void k_inproj(const float* __restrict__ xhat,
                                                const float* __restrict__ Wn,
                                                float* __restrict__ xi, float* __restrict__ g){
  __shared__ float Xs[64*68];
  __shared__ float Ws[64*68];
  int pb = blockIdx.x;   // 128 position blocks of 64
  int cb = blockIdx.y;   // 16 col blocks of 64 (1024 cols total)
  int tid = threadIdx.x;
  const float* xg = xhat + pb*64*64;
  const float* wg = Wn   + cb*64*64;
  for (int i=0;i<4;i++){
    int f4 = i*256 + tid;            // 1024 float4s per tile
    int r = f4 >> 4;
    int kk = (f4 & 15) << 2;
    *(float4*)&Xs[r*68+kk] = ((const float4*)xg)[f4];
    *(float4*)&Ws[r*68+kk] = ((const float4*)wg)[f4];
  }
  __syncthreads();
  int ty = tid >> 4, tx = tid & 15;
  float acc[4][4] = {};
  for (int k4=0;k4<16;k4++){
    float4 a[4], b[4];
    for (int i=0;i<4;i++) a[i] = *(float4*)&Xs[(ty*4+i)*68 + k4*4];
    for (int j=0;j<4;j++) b[j] = *(float4*)&Ws[(tx*4+j)*68 + k4*4];
    for (int i=0;i<4;i++) for (int j=0;j<4;j++)
      acc[i][j] += a[i].x*b[j].x + a[i].y*b[j].y + a[i].z*b[j].z + a[i].w*b[j].w;
  }
  for (int i=0;i<4;i++){
    int p = pb*64 + ty*4+i;
    int b_ = p >> 11;
    int l  = p & 2047;
    for (int j=0;j<4;j++){
      int col = cb*64 + tx*4+j;
      int dir = col >> 9;
      int e   = col & 511;
      float v = acc[i][j];
      int base = ((dir*BB + b_)*LL + l)*256;
      if (e < 256) xi[base + e] = v;
      else         g[base + (e-256)] = v * sigmoidf_(v);   // silu(z)
    }
  }
}

// ---------------- K2: depthwise causal/anticausal conv + SiLU -------------------
__global__ void k_conv(const float* __restrict__ xi,
                       const float* __restrict__ cwf, const float* __restrict__ cbf,
                       const float* __restrict__ cwb, const float* __restrict__ cbb,
                       float* __restrict__ xc){
  int pos = blockIdx.x;        // 0 .. 2*B*L-1
  int d = threadIdx.x;
  int dir = pos >> 13;         // /8192
  int bl = pos & 8191;
  int b = bl >> 11; int l = bl & 2047;
  const float* cw = dir ? cwb : cwf;
  const float* cb = dir ? cbb : cbf;
  float w0=cw[d*4+0], w1=cw[d*4+1], w2=cw[d*4+2], w3=cw[d*4+3];
  int base = ((dir*BB + b)*LL)*256;
  float acc = cb[d];
  if (dir==0){                  // taps l-3..l with w0..w3
    if (l>=3) acc += w0*xi[base+(l-3)*256+d];
    if (l>=2) acc += w1*xi[base+(l-2)*256+d];
    if (l>=1) acc += w2*xi[base+(l-1)*256+d];
    acc += w3*xi[base+l*256+d];
  } else {                      // anti-causal: taps l..l+3 with w3..w0
    acc += w3*xi[base+l*256+d];
    if (l+1<LL) acc += w2*xi[base+(l+1)*256+d];
    if (l+2<LL) acc += w1*xi[base+(l+2)*256+d];
    if (l+3<LL) acc += w0*xi[base+(l+3)*256+d];
  }
  acc = acc * sigmoidf_(acc);
  xc[base + l*256 + d] = acc;
}

// ---------------- K3: x_proj (36x256) + dt_proj + softplus ----------------------
__global__ __launch_bounds__(256) void k_xproj(const float* __restrict__ xc,
                        const float* __restrict__ xwf, const float* __restrict__ xwb,
                        const float* __restrict__ dtwf, const float* __restrict__ dtbf,
                        const float* __restrict__ dtwb, const float* __restrict__ dtbb,
                        float* __restrict__ dt, float* __restrict__ BC){
  __shared__ float xs[16*256];
  __shared__ float dbc[16][40];
  int blk = blockIdx.x;            // (dir, b, posblock16): 2*4*128 = 1024
  int pb = blk & 127;
  int b  = (blk>>7)&3;
  int dir= blk>>9;
  int tid = threadIdx.x;
  int base = ((dir*BB + b)*LL + pb*16)*256;
  for (int i=0;i<4;i++)
    ((float4*)xs)[i*256+tid] = ((const float4*)(xc+base))[i*256+tid];
  __syncthreads();
  const float* xw = dir ? xwb : xwf;
  for (int idx = tid; idx < 16*36; idx += 256){
    int p = idx / 36; int e = idx % 36;
    const float* wr = xw + e*256;
    const float* xr = xs + p*256;
    float s = 0.f;
    for (int k=0;k<256;k+=4)
      s += wr[k]*xr[k] + wr[k+1]*xr[k+1] + wr[k+2]*xr[k+2] + wr[k+3]*xr[k+3];
    dbc[p][e] = s;
  }
  __syncthreads();
  const float* dtw = dir ? dtwb : dtwf;
  const float* dtbp = dir ? dtbb : dtbf;
  int d = tid;
  float w0=dtw[d*4], w1=dtw[d*4+1], w2=dtw[d*4+2], w3=dtw[d*4+3], bias=dtbp[d];
  for (int p=0;p<16;p++){
    float s = bias + w0*dbc[p][0] + w1*dbc[p][1] + w2*dbc[p][2] + w3*dbc[p][3];
    float sp = (s > 20.0f) ? s : log1pf(__expf(s));
    dt[base + p*256 + d] = sp;
  }
  for (int idx = tid; idx < 16*32; idx += 256){
    int p = idx >> 5; int e = idx & 31;
    BC[((dir*BB+b)*LL + pb*16 + p)*32 + e] = dbc[p][4+e];
  }
}

// ---------------- K4: scan pass A — chunk-local h (h0=0) + sum(dt) --------------
__global__ __launch_bounds__(256) void k_scan1(const float* __restrict__ dt, const float* __restrict__ xc,
                        const float* __restrict__ BC,
                        const float* __restrict__ Alogf, const float* __restrict__ Alogb,
                        float* __restrict__ hloc, float* __restrict__ sums){
  __shared__ float Bs[TCH*16];
  int blk = blockIdx.x;            // 2*4*64 = 512: c | b | dir
  int c = blk & 63; int b = (blk>>6)&3; int dir = blk>>8;
  int tid = threadIdx.x;
  int seqbase = (dir*BB+b)*LL;
  for (int idx = tid; idx < TCH*16; idx += 256){
    int t = idx >> 4; int n = idx & 15;
    int gt = c*TCH + t;
    int l = dir ? (LL-1-gt) : gt;
    Bs[idx] = BC[(seqbase + l)*32 + n];
  }
  __syncthreads();
  int d = tid;
  const float* Alog = dir ? Alogb : Alogf;
  float A[16];
  for (int n=0;n<16;n++) A[n] = -__expf(Alog[d*16+n]);
  float h[16] = {};
  float sdt = 0.f;
  for (int t=0;t<TCH;t++){
    int gt = c*TCH + t;
    int l = dir ? (LL-1-gt) : gt;
    float dtv = dt[(seqbase+l)*256 + d];
    float xcv = xc[(seqbase+l)*256 + d];
    float u = dtv*xcv;
    sdt += dtv;
    for (int n=0;n<16;n++){
      float e = __expf(dtv*A[n]);
      h[n] = e*h[n] + u*Bs[t*16+n];
    }
  }
  int hb = (((dir*BB+b)*NCH + c)*256 + d)*16;
  for (int n=0;n<16;n+=4)
    *(float4*)&hloc[hb+n] = make_float4(h[n],h[n+1],h[n+2],h[n+3]);
  sums[((dir*BB+b)*NCH + c)*256 + d] = sdt;
}

// ---------------- K5: inter-chunk combine (P = exp(A*sum_dt) telescoping) -------
__global__ __launch_bounds__(256) void k_scan2(const float* __restrict__ hloc, const float* __restrict__ sums,
                        const float* __restrict__ Alogf, const float* __restrict__ Alogb,
                        float* __restrict__ hinit){
  int blk = blockIdx.x;            // 8: dir*4+b
  int b = blk & 3; int dir = blk >> 2;
  int d = threadIdx.x;
  const float* Alog = dir ? Alogb : Alogf;
  float A[16];
  for (int n=0;n<16;n++) A[n] = -__expf(Alog[d*16+n]);
  float h[16] = {};
  for (int c=0;c<NCH;c++){
    int hb = (((dir*BB+b)*NCH + c)*256 + d)*16;
    for (int n=0;n<16;n+=4)
      *(float4*)&hinit[hb+n] = make_float4(h[n],h[n+1],h[n+2],h[n+3]);
    float sdt = sums[((dir*BB+b)*NCH + c)*256 + d];
    float hl[16];
    for (int n=0;n<16;n+=4){
      float4 t4 = *(const float4*)&hloc[hb+n];
      hl[n]=t4.x; hl[n+1]=t4.y; hl[n+2]=t4.z; hl[n+3]=t4.w;
    }
    for (int n=0;n<16;n++)
      h[n] = __expf(A[n]*sdt)*h[n] + hl[n];
  }
}

// ---------------- K6: scan pass B — y, D skip, z gating -------------------------
__global__ __launch_bounds__(256) void k_scan3(const float* __restrict__ dt, const float* __restrict__ xc,
                        const float* __restrict__ g, const float* __restrict__ BC,
                        const float* __restrict__ Alogf, const float* __restrict__ Alogb,
                        const float* __restrict__ Df, const float* __restrict__ Db,
                        const float* __restrict__ hinit, float* __restrict__ yw){
  __shared__ float BCs[TCH*32];
  int blk = blockIdx.x;
  int c = blk & 63; int b = (blk>>6)&3; int dir = blk>>8;
  int tid = threadIdx.x;
  int seqbase = (dir*BB+b)*LL;
  for (int idx = tid; idx < TCH*32; idx += 256){
    int t = idx >> 5; int e = idx & 31;
    int gt = c*TCH + t;
    int l = dir ? (LL-1-gt) : gt;
    BCs[idx] = BC[(seqbase+l)*32 + e];
  }
  __syncthreads();
  int d = tid;
  const float* Alog = dir ? Alogb : Alogf;
  float A[16];
  for (int n=0;n<16;n++) A[n] = -__expf(Alog[d*16+n]);
  float Dp = dir ? Db[d] : Df[d];
  int hb = (((dir*BB+b)*NCH + c)*256 + d)*16;
  float h[16];
  for (int n=0;n<16;n+=4){
    float4 t4 = *(const float4*)&hinit[hb+n];
    h[n]=t4.x; h[n+1]=t4.y; h[n+2]=t4.z; h[n+3]=t4.w;
  }
  for (int t=0;t<TCH;t++){
    int gt = c*TCH+t;
    int l = dir ? (LL-1-gt) : gt;
    int off = (seqbase+l)*256 + d;
    float dtv = dt[off];
    float xcv = xc[off];
    float gv  = g[off];
    float u = dtv*xcv;
    float y = 0.f;
    for (int n=0;n<16;n++){
      float e = __expf(dtv*A[n]);
      h[n] = e*h[n] + u*BCs[t*32+n];
      y += h[n]*BCs[t*32+16+n];
    }
    y = (y + Dp*xcv)*gv;
    yw[off] = y;
  }
}

// ---------------- K7: out_proj GEMM + residual ----------------------------------
__global__ __launch_bounds__(256) void k_outproj(const float* __restrict__ yw,
                          const float* __restrict__ owf, const float* __restrict__ owb,
                          const float* __restrict__ x, float* __restrict__ out){
  __shared__ float Ys[64*68];
  __shared__ float Wls[64*68];
  int pb = blockIdx.x;  // 128
  int dir = blockIdx.y; // 2
  int tid = threadIdx.x;
  int ty = tid>>4, tx = tid&15;
  int p0 = pb*64;
  int b = p0 >> 11; int l0 = p0 & 2047;
  const float* ow = dir ? owb : owf;
  int ybase = ((dir*BB+b)*LL + l0)*256;
  float acc[4][4] = {};
  for (int ks=0; ks<4; ks++){
    for (int i=0;i<4;i++){
      int f4 = i*256+tid;
      int r = f4>>4; int kk = (f4&15)<<2;
      *(float4*)&Ys[r*68+kk]  = *(const float4*)&yw[ybase + r*256 + ks*64 + kk];
      *(float4*)&Wls[r*68+kk] = *(const float4*)&ow[r*256 + ks*64 + kk];
    }
    __syncthreads();
    for (int k4=0;k4<16;k4++){
      float4 a[4], bb[4];
      for (int i=0;i<4;i++) a[i]  = *(float4*)&Ys[(ty*4+i)*68 + k4*4];
      for (int j=0;j<4;j++) bb[j] = *(float4*)&Wls[(tx*4+j)*68 + k4*4];
      for (int i=0;i<4;i++) for (int j=0;j<4;j++)
        acc[i][j] += a[i].x*bb[j].x + a[i].y*bb[j].y + a[i].z*bb[j].z + a[i].w*bb[j].w;
    }
    __syncthreads();
  }
  for (int i=0;i<4;i++){
    int l = l0 + ty*4+i;
    for (int j=0;j<4;j++){
      int o = tx*4+j;
      out[(b*LL+l)*128 + dir*64 + o] = acc[i][j] + x[(b*LL+l)*64 + o];
    }
  }
}

extern "C" void kernel_launch(void* const* d_in, const int* in_sizes, int n_in,
                              void* d_out, int out_size, void* d_ws, size_t ws_size,
                              hipStream_t stream){
  const float* x       = (const float*)d_in[0];
  const float* nwf     = (const float*)d_in[1];
  const float* inwf    = (const float*)d_in[2];
  const float* cwf     = (const float*)d_in[3];
  const float* cbf     = (const float*)d_in[4];
  const float* xwf     = (const float*)d_in[5];
  const float* dtwf    = (const float*)d_in[6];
  const float* dtbf    = (const float*)d_in[7];
  const float* Alogf   = (const float*)d_in[8];
  const float* Df      = (const float*)d_in[9];
  const float* owf     = (const float*)d_in[10];
  const float* nwb     = (const float*)d_in[11];
  const float* inwb    = (const float*)d_in[12];
  const float* cwb     = (const float*)d_in[13];
  const float* cbb     = (const float*)d_in[14];
  const float* xwb     = (const float*)d_in[15];
  const float* dtwb    = (const float*)d_in[16];
  const float* dtbb    = (const float*)d_in[17];
  const float* Alogb   = (const float*)d_in[18];
  const float* Db      = (const float*)d_in[19];
  const float* owb     = (const float*)d_in[20];
  float* out = (float*)d_out;

  float* ws    = (float*)d_ws;
  float* xhat  = ws;                    // B*L*64        = 524288
  float* Wn    = xhat  + 524288;        // 2*512*64      = 65536
  float* xi    = Wn    + 65536;         // 2*B*L*256     = 4194304
  float* g     = xi    + 4194304;
  float* xcb   = g     + 4194304;
  float* dtb   = xcb   + 4194304;
  float* BC    = dtb   + 4194304;       // 2*B*L*32      = 524288
  float* hloc  = BC    + 524288;        // 2*B*NCH*256*16= 2097152
  float* sums  = hloc  + 2097152;       // 2*B*NCH*256   = 131072
  float* hinit = sums  + 131072;        // 2097152
  float* yw    = xi;                    // reuse: xi dead after k_conv

  k_rmsnorm<<<BB*LL, 64, 0, stream>>>(x, xhat);
  k_fold<<<256, 256, 0, stream>>>(inwf, nwf, inwb, nwb, Wn);
  k_inproj<<<dim3(128,16), 256, 0, stream>>>(xhat, Wn, xi, g);
  k_conv<<<2*BB*LL, 256, 0, stream>>>(xi, cwf, cbf, cwb, cbb, xcb);
  k_xproj<<<1024, 256, 0, stream>>>(xcb, xwf, xwb, dtwf, dtbf, dtwb, dtbb, dtb, BC);
  k_scan1<<<512, 256, 0, stream>>>(dtb, xcb, BC, Alogf, Alogb, hloc, sums);
  k_scan2<<<8, 256, 0, stream>>>(hloc, sums, Alogf, Alogb, hinit);
  k_scan3<<<512, 256, 0, stream>>>(dtb, xcb, g, BC, Alogf, Alogb, Df, Db, hinit, yw);
  k_outproj<<<dim3(128,2), 256, 0, stream>>>(yw, owf, owb, x, out);
}

// Round 2
// 289.844 us; speedup vs baseline: 1.1896x; 1.1896x over previous
//
#include <hip/hip_runtime.h>
#include <math.h>

#define BB 4
#define LL 2048
#define TCH 32          // scan chunk length
#define NCH (LL/TCH)    // 64 chunks per sequence

__device__ __forceinline__ float sigmoidf_(float x){ return 1.0f/(1.0f+__expf(-x)); }

// ---- K1: fused rmsnorm + weight-fold + in_proj GEMM (8192x64 @ 64x1024) --------
__global__ __launch_bounds__(256) void k_inproj(const float* __restrict__ x,
                                                const float* __restrict__ nwf,
                                                const float* __restrict__ nwb,
                                                const float* __restrict__ inwf,
                                                const float* __restrict__ inwb,
                                                float* __restrict__ xi, float* __restrict__ g){
  __shared__ float Xs[64*68];
  __shared__ float Ws[64*68];
  int pb = blockIdx.x;   // 128 position blocks of 64
  int cb = blockIdx.y;   // 16 col blocks of 64 (1024 cols total)
  int tid = threadIdx.x;
  int dirw = cb>>3;
  const float* xg = x + pb*64*64;
  const float* wg = (dirw ? inwb : inwf) + (cb&7)*64*64;
  const float* nw = dirw ? nwb : nwf;
  for (int i=0;i<4;i++){
    int f4 = i*256 + tid;            // 1024 float4s per tile
    int r = f4 >> 4;
    int kk = (f4 & 15) << 2;
    *(float4*)&Xs[r*68+kk] = ((const float4*)xg)[f4];
    float4 w4 = ((const float4*)wg)[f4];
    float4 n4 = *(const float4*)&nw[kk];
    w4.x*=n4.x; w4.y*=n4.y; w4.z*=n4.z; w4.w*=n4.w;
    *(float4*)&Ws[r*68+kk] = w4;
  }
  __syncthreads();
  { // rmsnorm in place: 4 threads per row, 16 elems each
    int r = tid>>2, q = tid&3;
    float s = 0.f;
    for (int i2=0;i2<16;i2++){ float v = Xs[r*68 + q*16 + i2]; s += v*v; }
    s += __shfl_xor(s, 1);
    s += __shfl_xor(s, 2);
    float rstd = rsqrtf(s*(1.0f/64.0f) + 1e-5f);
    for (int i2=0;i2<16;i2++) Xs[r*68 + q*16 + i2] *= rstd;
  }
  __syncthreads();
  int ty = tid >> 4, tx = tid & 15;
  float acc[4][4] = {};
  for (int k4=0;k4<16;k4++){
    float4 a[4], b[4];
    for (int i=0;i<4;i++) a[i] = *(float4*)&Xs[(ty*4+i)*68 + k4*4];
    for (int j=0;j<4;j++) b[j] = *(float4*)&Ws[(tx*4+j)*68 + k4*4];
    for (int i=0;i<4;i++) for (int j=0;j<4;j++)
      acc[i][j] += a[i].x*b[j].x + a[i].y*b[j].y + a[i].z*b[j].z + a[i].w*b[j].w;
  }
  for (int i=0;i<4;i++){
    int p = pb*64 + ty*4+i;
    int b_ = p >> 11;
    int l  = p & 2047;
    for (int j=0;j<4;j++){
      int col = cb*64 + tx*4+j;
      int dir = col >> 9;
      int e   = col & 511;
      float v = acc[i][j];
      int base = ((dir*BB + b_)*LL + l)*256;
      if (e < 256) xi[base + e] = v;
      else         g[base + (e-256)] = v * sigmoidf_(v);   // silu(z)
    }
  }
}

// ---- K2: depthwise conv + SiLU, register sliding window -------------------------
// In reversed coordinates (t = dir? LL-1-l : l) both directions are the same
// causal conv y[t] = c3 x[t] + c2 x[t-1] + c1 x[t-2] + c0 x[t-3], zero-padded.
__global__ __launch_bounds__(256) void k_conv(const float* __restrict__ xi,
                       const float* __restrict__ cwf, const float* __restrict__ cbf,
                       const float* __restrict__ cwb, const float* __restrict__ cbb,
                       float* __restrict__ xc){
  int blk = blockIdx.x;           // 512: tile(64) | b(4) | dir(2); 2048/32 = 64 tiles
  int tile = blk & 63; int b = (blk>>6)&3; int dir = blk>>8;
  int d = threadIdx.x;
  const float* cw  = dir ? cwb : cwf;
  const float* cbv = dir ? cbb : cbf;
  float c0=cw[d*4+0], c1=cw[d*4+1], c2=cw[d*4+2], c3=cw[d*4+3];
  float bias = cbv[d];
  const float* base = xi + ((dir*BB+b)*LL)*256;
  float*       obase= xc + ((dir*BB+b)*LL)*256;
  int t0 = tile*32;
  #define CIDX(t) ((dir ? (LL-1-(t)) : (t))*256 + d)
  float m1 = (t0-1>=0) ? base[CIDX(t0-1)] : 0.f;
  float m2 = (t0-2>=0) ? base[CIDX(t0-2)] : 0.f;
  float m3 = (t0-3>=0) ? base[CIDX(t0-3)] : 0.f;
  for (int t=t0; t<t0+32; t+=4){
    float x0 = base[CIDX(t)];
    float x1 = base[CIDX(t+1)];
    float x2 = base[CIDX(t+2)];
    float x3 = base[CIDX(t+3)];
    float a0 = bias + c3*x0 + c2*m1 + c1*m2 + c0*m3;
    float a1 = bias + c3*x1 + c2*x0 + c1*m1 + c0*m2;
    float a2 = bias + c3*x2 + c2*x1 + c1*x0 + c0*m1;
    float a3 = bias + c3*x3 + c2*x2 + c1*x1 + c0*x0;
    a0 *= sigmoidf_(a0); a1 *= sigmoidf_(a1);
    a2 *= sigmoidf_(a2); a3 *= sigmoidf_(a3);
    obase[CIDX(t)]   = a0;
    obase[CIDX(t+1)] = a1;
    obase[CIDX(t+2)] = a2;
    obase[CIDX(t+3)] = a3;
    m1 = x3; m2 = x2; m3 = x1;
  }
  #undef CIDX
}

// ---- K3: x_proj (36x256) + dt_proj + softplus, bank-conflict-free ---------------
// 32 positions/block. X in LDS rows padded to 257 -> (p+k)%32 banks, <=2-way.
// e is wave-uniform (wave w handles e=w+4j); lanes split (p, k-half);
// cross-half combine via shfl_xor(32).
__global__ __launch_bounds__(256) void k_xproj(const float* __restrict__ xc,
                        const float* __restrict__ xwf, const float* __restrict__ xwb,
                        const float* __restrict__ dtwf, const float* __restrict__ dtbf,
                        const float* __restrict__ dtwb, const float* __restrict__ dtbb,
                        float* __restrict__ dt, float* __restrict__ BC){
  __shared__ float xs[32*257];
  __shared__ float dbcs[32*41];
  int blk = blockIdx.x;            // 512 blocks; gbase spans [dir][b][l] linearly
  int gbase = blk*32;
  int dir = blk >> 8;
  int tid = threadIdx.x;
  const float4* src = (const float4*)(xc + gbase*256);
  for (int i=0;i<8;i++){
    int flat = i*256 + tid;        // 0..2047 float4s
    int k4 = (flat&7) | (((flat>>6)&7)<<3);
    int p  = ((flat>>3)&7) | ((flat>>9)<<3);
    float4 v = src[p*64 + k4];
    float* dst = &xs[p*257 + k4*4];
    dst[0]=v.x; dst[1]=v.y; dst[2]=v.z; dst[3]=v.w;
  }
  __syncthreads();
  int wv = tid>>6; int lane = tid&63;
  int p = lane & 31; int kh = lane >> 5;   // k-half: 0 -> k<128, 1 -> k>=128
  const float* xw = dir ? xwb : xwf;
  float acc[9];
  #pragma unroll
  for (int j=0;j<9;j++) acc[j]=0.f;
  const float* xrow = &xs[p*257 + kh*128];
  for (int k4=0;k4<32;k4++){
    float x0=xrow[k4*4+0], x1=xrow[k4*4+1], x2=xrow[k4*4+2], x3=xrow[k4*4+3];
    #pragma unroll
    for (int j=0;j<9;j++){
      int e = wv + 4*j;            // wave-uniform
      float4 w4 = *(const float4*)&xw[e*256 + kh*128 + k4*4];
      acc[j] += w4.x*x0 + w4.y*x1 + w4.z*x2 + w4.w*x3;
    }
  }
  #pragma unroll
  for (int j=0;j<9;j++){
    float v = acc[j] + __shfl_xor(acc[j], 32);
    if (kh==0) dbcs[p*41 + wv + 4*j] = v;
  }
  __syncthreads();
  // dt_proj + softplus: each thread owns one d, loops positions (broadcast LDS reads)
  const float* dtw  = dir ? dtwb : dtwf;
  const float* dtbp = dir ? dtbb : dtbf;
  {
    int d = tid;
    float4 w4 = *(const float4*)&dtw[d*4];
    float bias = dtbp[d];
    for (int p2=0;p2<32;p2++){
      float s = bias + w4.x*dbcs[p2*41+0] + w4.y*dbcs[p2*41+1]
                     + w4.z*dbcs[p2*41+2] + w4.w*dbcs[p2*41+3];
      float sp = (s > 20.0f) ? s : log1pf(__expf(s));
      dt[(gbase+p2)*256 + d] = sp;
    }
  }
  // BC writeout: contiguous
  for (int i=0;i<4;i++){
    int idx = i*256 + tid;         // 0..1023
    int e = idx & 31; int p2 = idx >> 5;
    BC[gbase*32 + idx] = dbcs[p2*41 + 4 + e];
  }
}

// ---- K4: scan pass A — chunk-local h (h0=0) + sum(dt) ---------------------------
__global__ __launch_bounds__(256) void k_scan1(const float* __restrict__ dt, const float* __restrict__ xc,
                        const float* __restrict__ BC,
                        const float* __restrict__ Alogf, const float* __restrict__ Alogb,
                        float* __restrict__ hloc, float* __restrict__ sums){
  __shared__ float Bs[TCH*16];
  int blk = blockIdx.x;            // 2*4*64 = 512: c | b | dir
  int c = blk & 63; int b = (blk>>6)&3; int dir = blk>>8;
  int tid = threadIdx.x;
  int seqbase = (dir*BB+b)*LL;
  for (int idx = tid; idx < TCH*16; idx += 256){
    int t = idx >> 4; int n = idx & 15;
    int gt = c*TCH + t;
    int l = dir ? (LL-1-gt) : gt;
    Bs[idx] = BC[(seqbase + l)*32 + n];
  }
  __syncthreads();
  int d = tid;
  const float* Alog = dir ? Alogb : Alogf;
  float A[16];
  for (int n=0;n<16;n++) A[n] = -__expf(Alog[d*16+n]);
  float h[16] = {};
  float sdt = 0.f;
  for (int t=0;t<TCH;t++){
    int gt = c*TCH + t;
    int l = dir ? (LL-1-gt) : gt;
    float dtv = dt[(seqbase+l)*256 + d];
    float xcv = xc[(seqbase+l)*256 + d];
    float u = dtv*xcv;
    sdt += dtv;
    for (int n=0;n<16;n++){
      float e = __expf(dtv*A[n]);
      h[n] = e*h[n] + u*Bs[t*16+n];
    }
  }
  int hb = (((dir*BB+b)*NCH + c)*256 + d)*16;
  for (int n=0;n<16;n+=4)
    *(float4*)&hloc[hb+n] = make_float4(h[n],h[n+1],h[n+2],h[n+3]);
  sums[((dir*BB+b)*NCH + c)*256 + d] = sdt;
}

// ---- K5: inter-chunk combine (P = exp(A*sum_dt) telescoping) --------------------
__global__ __launch_bounds__(256) void k_scan2(const float* __restrict__ hloc, const float* __restrict__ sums,
                        const float* __restrict__ Alogf, const float* __restrict__ Alogb,
                        float* __restrict__ hinit){
  int blk = blockIdx.x;            // 8: dir*4+b
  int b = blk & 3; int dir = blk >> 2;
  int d = threadIdx.x;
  const float* Alog = dir ? Alogb : Alogf;
  float A[16];
  for (int n=0;n<16;n++) A[n] = -__expf(Alog[d*16+n]);
  float h[16] = {};
  for (int c=0;c<NCH;c++){
    int hb = (((dir*BB+b)*NCH + c)*256 + d)*16;
    for (int n=0;n<16;n+=4)
      *(float4*)&hinit[hb+n] = make_float4(h[n],h[n+1],h[n+2],h[n+3]);
    float sdt = sums[((dir*BB+b)*NCH + c)*256 + d];
    float hl[16];
    for (int n=0;n<16;n+=4){
      float4 t4 = *(const float4*)&hloc[hb+n];
      hl[n]=t4.x; hl[n+1]=t4.y; hl[n+2]=t4.z; hl[n+3]=t4.w;
    }
    for (int n=0;n<16;n++)
      h[n] = __expf(A[n]*sdt)*h[n] + hl[n];
  }
}

// ---- K6: scan pass B — y, D skip, z gating --------------------------------------
__global__ __launch_bounds__(256) void k_scan3(const float* __restrict__ dt, const float* __restrict__ xc,
                        const float* __restrict__ g, const float* __restrict__ BC,
                        const float* __restrict__ Alogf, const float* __restrict__ Alogb,
                        const float* __restrict__ Df, const float* __restrict__ Db,
                        const float* __restrict__ hinit, float* __restrict__ yw){
  __shared__ float BCs[TCH*32];
  int blk = blockIdx.x;
  int c = blk & 63; int b = (blk>>6)&3; int dir = blk>>8;
  int tid = threadIdx.x;
  int seqbase = (dir*BB+b)*LL;
  for (int idx = tid; idx < TCH*32; idx += 256){
    int t = idx >> 5; int e = idx & 31;
    int gt = c*TCH + t;
    int l = dir ? (LL-1-gt) : gt;
    BCs[idx] = BC[(seqbase+l)*32 + e];
  }
  __syncthreads();
  int d = tid;
  const float* Alog = dir ? Alogb : Alogf;
  float A[16];
  for (int n=0;n<16;n++) A[n] = -__expf(Alog[d*16+n]);
  float Dp = dir ? Db[d] : Df[d];
  int hb = (((dir*BB+b)*NCH + c)*256 + d)*16;
  float h[16];
  for (int n=0;n<16;n+=4){
    float4 t4 = *(const float4*)&hinit[hb+n];
    h[n]=t4.x; h[n+1]=t4.y; h[n+2]=t4.z; h[n+3]=t4.w;
  }
  for (int t=0;t<TCH;t++){
    int gt = c*TCH+t;
    int l = dir ? (LL-1-gt) : gt;
    int off = (seqbase+l)*256 + d;
    float dtv = dt[off];
    float xcv = xc[off];
    float gv  = g[off];
    float u = dtv*xcv;
    float y = 0.f;
    for (int n=0;n<16;n++){
      float e = __expf(dtv*A[n]);
      h[n] = e*h[n] + u*BCs[t*32+n];
      y += h[n]*BCs[t*32+16+n];
    }
    y = (y + Dp*xcv)*gv;
    yw[off] = y;
  }
}

// ---- K7: out_proj GEMM + residual ----------------------------------------------
__global__ __launch_bounds__(256) void k_outproj(const float* __restrict__ yw,
                          const float* __restrict__ owf, const float* __restrict__ owb,
                          const float* __restrict__ x, float* __restrict__ out){
  __shared__ float Ys[64*68];
  __shared__ float Wls[64*68];
  int pb = blockIdx.x;  // 128
  int dir = blockIdx.y; // 2
  int tid = threadIdx.x;
  int ty = tid>>4, tx = tid&15;
  int p0 = pb*64;
  int b = p0 >> 11; int l0 = p0 & 2047;
  const float* ow = dir ? owb : owf;
  int ybase = ((dir*BB+b)*LL + l0)*256;
  float acc[4][4] = {};
  for (int ks=0; ks<4; ks++){
    for (int i=0;i<4;i++){
      int f4 = i*256+tid;
      int r = f4>>4; int kk = (f4&15)<<2;
      *(float4*)&Ys[r*68+kk]  = *(const float4*)&yw[ybase + r*256 + ks*64 + kk];
      *(float4*)&Wls[r*68+kk] = *(const float4*)&ow[r*256 + ks*64 + kk];
    }
    __syncthreads();
    for (int k4=0;k4<16;k4++){
      float4 a[4], bb[4];
      for (int i=0;i<4;i++) a[i]  = *(float4*)&Ys[(ty*4+i)*68 + k4*4];
      for (int j=0;j<4;j++) bb[j] = *(float4*)&Wls[(tx*4+j)*68 + k4*4];
      for (int i=0;i<4;i++) for (int j=0;j<4;j++)
        acc[i][j] += a[i].x*bb[j].x + a[i].y*bb[j].y + a[i].z*bb[j].z + a[i].w*bb[j].w;
    }
    __syncthreads();
  }
  for (int i=0;i<4;i++){
    int l = l0 + ty*4+i;
    for (int j=0;j<4;j++){
      int o = tx*4+j;
      out[(b*LL+l)*128 + dir*64 + o] = acc[i][j] + x[(b*LL+l)*64 + o];
    }
  }
}

extern "C" void kernel_launch(void* const* d_in, const int* in_sizes, int n_in,
                              void* d_out, int out_size, void* d_ws, size_t ws_size,
                              hipStream_t stream){
  const float* x       = (const float*)d_in[0];
  const float* nwf     = (const float*)d_in[1];
  const float* inwf    = (const float*)d_in[2];
  const float* cwf     = (const float*)d_in[3];
  const float* cbf     = (const float*)d_in[4];
  const float* xwf     = (const float*)d_in[5];
  const float* dtwf    = (const float*)d_in[6];
  const float* dtbf    = (const float*)d_in[7];
  const float* Alogf   = (const float*)d_in[8];
  const float* Df      = (const float*)d_in[9];
  const float* owf     = (const float*)d_in[10];
  const float* nwb     = (const float*)d_in[11];
  const float* inwb    = (const float*)d_in[12];
  const float* cwb     = (const float*)d_in[13];
  const float* cbb     = (const float*)d_in[14];
  const float* xwb     = (const float*)d_in[15];
  const float* dtwb    = (const float*)d_in[16];
  const float* dtbb    = (const float*)d_in[17];
  const float* Alogb   = (const float*)d_in[18];
  const float* Db      = (const float*)d_in[19];
  const float* owb     = (const float*)d_in[20];
  float* out = (float*)d_out;

  float* ws    = (float*)d_ws;
  float* xi    = ws;                    // 2*B*L*256     = 4194304
  float* g     = xi    + 4194304;
  float* xcb   = g     + 4194304;
  float* dtb   = xcb   + 4194304;
  float* BC    = dtb   + 4194304;       // 2*B*L*32      = 524288
  float* hloc  = BC    + 524288;        // 2*B*NCH*256*16= 2097152
  float* sums  = hloc  + 2097152;       // 2*B*NCH*256   = 131072
  float* hinit = sums  + 131072;        // 2097152
  float* yw    = xi;                    // reuse: xi dead after k_conv

  k_inproj<<<dim3(128,16), 256, 0, stream>>>(x, nwf, nwb, inwf, inwb, xi, g);
  k_conv<<<512, 256, 0, stream>>>(xi, cwf, cbf, cwb, cbb, xcb);
  k_xproj<<<512, 256, 0, stream>>>(xcb, xwf, xwb, dtwf, dtbf, dtwb, dtbb, dtb, BC);
  k_scan1<<<512, 256, 0, stream>>>(dtb, xcb, BC, Alogf, Alogb, hloc, sums);
  k_scan2<<<8, 256, 0, stream>>>(hloc, sums, Alogf, Alogb, hinit);
  k_scan3<<<512, 256, 0, stream>>>(dtb, xcb, g, BC, Alogf, Alogb, Df, Db, hinit, yw);
  k_outproj<<<dim3(128,2), 256, 0, stream>>>(yw, owf, owb, x, out);
}